// Round 4
// baseline (293.797 us; speedup 1.0000x reference)
//
#include <hip/hip_runtime.h>

typedef unsigned short u16;
typedef __attribute__((ext_vector_type(8))) short bf16x8;
typedef __attribute__((ext_vector_type(4))) float f32x4;

#define AS1 __attribute__((address_space(1)))
#define AS3 __attribute__((address_space(3)))

__device__ __forceinline__ void gld16(const void* g, void* l) {
    __builtin_amdgcn_global_load_lds((const AS1 void*)g, (AS3 void*)l, 16, 0, 0);
}

__device__ __forceinline__ u16 f2bf(float f) {
    unsigned int u = __float_as_uint(f);
    unsigned int r = (u >> 16) & 1u;
    u += 0x7fffu + r;
    return (u16)(u >> 16);
}

__device__ __forceinline__ float gelu_exact(float v) {
    return 0.5f * v * (1.0f + erff(v * 0.70710678118654752f));
}

// ---------------- W1 transpose + cast: W[R][C] f32 -> Wt[C][R] bf16 ----------
__global__ __launch_bounds__(256) void transpose_cast(
    const float* __restrict__ W, u16* __restrict__ Wt, int R, int C) {
    __shared__ float t[32][33];
    const int tx = threadIdx.x & 31, tg = threadIdx.x >> 5;
    const int c0 = blockIdx.x * 32, r0 = blockIdx.y * 32;
#pragma unroll
    for (int i = 0; i < 4; ++i) {
        int rr = tg + i * 8;
        t[rr][tx] = W[(long)(r0 + rr) * C + c0 + tx];
    }
    __syncthreads();
#pragma unroll
    for (int i = 0; i < 4; ++i) {
        int rr = tg + i * 8;
        Wt[(long)(c0 + rr) * R + r0 + tx] = f2bf(t[tx][rr]);
    }
}

// ---------------- TT core contraction ----------------------------------------
__global__ __launch_bounds__(256) void tt_m1_kernel(
    const float* __restrict__ g1, const float* __restrict__ g2,
    float* __restrict__ M1) {
    const int id = blockIdx.x * 256 + threadIdx.x;       // 262144
    const int t = id & 15, q = (id >> 4) & 15, p = (id >> 8) & 7;
    const int j = (id >> 11) & 15, i = id >> 15;
    float acc = 0.f;
#pragma unroll
    for (int s = 0; s < 16; ++s)
        acc += g1[(i * 8 + p) * 16 + s] * g2[((s * 16 + j) * 16 + q) * 16 + t];
    M1[id] = acc;
}

__global__ __launch_bounds__(256) void tt_w2t_kernel(
    const float* __restrict__ M1, const float* __restrict__ g3,
    u16* __restrict__ W2T) {
    const int id = blockIdx.x * 256 + threadIdx.x;       // 2097152
    const int fi = id & 2047, fo = id >> 11;
    const int i = fi >> 8, j = (fi >> 4) & 15, k = fi & 15;
    const int p = fo >> 7, q = (fo >> 3) & 15, u = fo & 7;
    const float* m = &M1[(((i * 16 + j) * 8 + p) * 16 + q) * 16];
    float acc = 0.f;
#pragma unroll
    for (int t = 0; t < 16; ++t)
        acc += m[t] * g3[(t * 16 + k) * 8 + u];
    W2T[id] = f2bf(acc);
}

// ---------------- LayerNorm 1: x f32 -> xln bf16 -----------------------------
__global__ __launch_bounds__(256) void ln1_kernel(
    const float* __restrict__ x, const float* __restrict__ gamma,
    const float* __restrict__ beta, u16* __restrict__ out) {
    const long row = blockIdx.x;
    const int tid = threadIdx.x;
    const float4 v = ((const float4*)(x + row * 1024))[tid];
    float s = v.x + v.y + v.z + v.w;
    float ss = v.x * v.x + v.y * v.y + v.z * v.z + v.w * v.w;
#pragma unroll
    for (int off = 32; off; off >>= 1) {
        s += __shfl_down(s, off, 64);
        ss += __shfl_down(ss, off, 64);
    }
    __shared__ float rs[4], rss[4];
    const int w = tid >> 6, lane = tid & 63;
    if (lane == 0) { rs[w] = s; rss[w] = ss; }
    __syncthreads();
    s = rs[0] + rs[1] + rs[2] + rs[3];
    ss = rss[0] + rss[1] + rss[2] + rss[3];
    const float mu = s * (1.0f / 1024.0f);
    const float var = ss * (1.0f / 1024.0f) - mu * mu;
    const float rstd = rsqrtf(var + 1e-5f);
    const float4 gm = ((const float4*)gamma)[tid];
    const float4 bt = ((const float4*)beta)[tid];
    ushort4 o;
    o.x = f2bf((v.x - mu) * rstd * gm.x + bt.x);
    o.y = f2bf((v.y - mu) * rstd * gm.y + bt.y);
    o.z = f2bf((v.z - mu) * rstd * gm.z + bt.z);
    o.w = f2bf((v.w - mu) * rstd * gm.w + bt.w);
    ((ushort4*)(out + row * 1024))[tid] = o;
}

// ---------------- LayerNorm 2 (in-place): z -> z + LN(z) ---------------------
__global__ __launch_bounds__(256) void ln2_kernel(
    float* __restrict__ z, const float* __restrict__ gamma,
    const float* __restrict__ beta) {
    const long row = blockIdx.x;
    const int tid = threadIdx.x;
    const float4 v = ((const float4*)(z + row * 1024))[tid];
    float s = v.x + v.y + v.z + v.w;
    float ss = v.x * v.x + v.y * v.y + v.z * v.z + v.w * v.w;
#pragma unroll
    for (int off = 32; off; off >>= 1) {
        s += __shfl_down(s, off, 64);
        ss += __shfl_down(ss, off, 64);
    }
    __shared__ float rs[4], rss[4];
    const int w = tid >> 6, lane = tid & 63;
    if (lane == 0) { rs[w] = s; rss[w] = ss; }
    __syncthreads();
    s = rs[0] + rs[1] + rs[2] + rs[3];
    ss = rss[0] + rss[1] + rss[2] + rss[3];
    const float mu = s * (1.0f / 1024.0f);
    const float var = ss * (1.0f / 1024.0f) - mu * mu;
    const float rstd = rsqrtf(var + 1e-5f);
    const float4 gm = ((const float4*)gamma)[tid];
    const float4 bt = ((const float4*)beta)[tid];
    float4 o;
    o.x = v.x + ((v.x - mu) * rstd * gm.x + bt.x);
    o.y = v.y + ((v.y - mu) * rstd * gm.y + bt.y);
    o.z = v.z + ((v.z - mu) * rstd * gm.z + bt.z);
    o.w = v.w + ((v.w - mu) * rstd * gm.w + bt.w);
    ((float4*)(z + row * 1024))[tid] = o;
}

// ---------------- 256x256 GEMM: C = A[M][K] @ Bt[N][K]^T ---------------------
// 512 threads (8 waves: 2M x 4N), BK=32, TRIPLE-buffered LDS, depth-2 staging
// prefetch, ONE barrier + counted vmcnt(4) per K-tile (never drain in-loop).
// Swizzle: byte ^= (row&3)<<4, applied on BOTH staging source and frag reads.
// EPI=0: out = bf16(gelu(acc + bias[col]))
// EPI=1: out = f32(acc + bias[col] + resid[row][col])
template <int EPI>
__global__ __launch_bounds__(512, 2) void gemm256(
    const u16* __restrict__ A, const u16* __restrict__ Bt,
    void* __restrict__ outp, const float* __restrict__ bias,
    const float* __restrict__ resid, int M, int N, int K) {
    __shared__ char smem[98304];    // 3 bufs x (A 16K + B 16K)
    const int tid = threadIdx.x;
    int b = blockIdx.x;
    const int nwg = gridDim.x;
    if ((nwg & 7) == 0 && nwg >= 8) {   // XCD-aware swizzle (bijective)
        const int per = nwg >> 3;
        b = (b & 7) * per + (b >> 3);
    }
    const int NT = N >> 8;
    const int mt = b / NT, nt = b - mt * NT;
    const long m0 = (long)mt << 8, n0 = (long)nt << 8;
    const int NTK = K >> 5;

    const int lane = tid & 63, wid = tid >> 6;
    const int wm = wid >> 2, wn = wid & 3;
    const int r = lane & 15, g = lane >> 4;

    // staging: linear LDS dest (gld16 requirement: wave-uniform base + lane*16),
    // source column pre-swizzled by the same involution the reads use.
    const int lin0 = tid * 16, lin1 = tid * 16 + 8192;
    const int sr0 = lin0 >> 6, sc0 = ((lin0 & 63) ^ (((lin0 >> 6) & 3) << 4)) >> 1;
    const int sr1 = lin1 >> 6, sc1 = ((lin1 & 63) ^ (((lin1 >> 6) & 3) << 4)) >> 1;

#define STAGE(kt, bi)                                                             \
    do {                                                                          \
        const int kc = (kt) < NTK ? (kt) : NTK - 1;                               \
        const long ko = (long)kc << 5;                                            \
        gld16(A + (m0 + sr0) * (long)K + ko + sc0, smem + (bi) * 32768 + lin0);   \
        gld16(A + (m0 + sr1) * (long)K + ko + sc1, smem + (bi) * 32768 + lin1);   \
        gld16(Bt + (n0 + sr0) * (long)K + ko + sc0,                               \
              smem + (bi) * 32768 + 16384 + lin0);                                \
        gld16(Bt + (n0 + sr1) * (long)K + ko + sc1,                               \
              smem + (bi) * 32768 + 16384 + lin1);                                \
    } while (0)

    // frag-read swizzle: row = (16*i + r) -> row&3 == r&3, per-thread constant
    const int ac = (g * 16) ^ ((r & 3) << 4);

    f32x4 acc[8][4] = {};

    // ---- prologue: stage tiles 0 and 1; wait tile 0 landed ----
    STAGE(0, 0);
    STAGE(1, 1);
    asm volatile("s_waitcnt vmcnt(4)" ::: "memory");
    __builtin_amdgcn_s_barrier();

    int b0 = 0, b1 = 1, b2 = 2;
    for (int t = 0; t < NTK; ++t) {
        STAGE(t + 2, b2);                 // depth-2 prefetch (clamped at tail)
        const char* Ab = smem + b0 * 32768 + wm * 8192;
        const char* Bb = smem + b0 * 32768 + 16384 + wn * 4096;
        bf16x8 af[8], bf_[4];
#pragma unroll
        for (int i = 0; i < 8; ++i)
            af[i] = *(const bf16x8*)(Ab + ((i * 16 + r) * 64 + ac));
#pragma unroll
        for (int j = 0; j < 4; ++j)
            bf_[j] = *(const bf16x8*)(Bb + ((j * 16 + r) * 64 + ac));
        __builtin_amdgcn_s_setprio(1);
#pragma unroll
        for (int i = 0; i < 8; ++i)
#pragma unroll
            for (int j = 0; j < 4; ++j)
                acc[i][j] = __builtin_amdgcn_mfma_f32_16x16x32_bf16(
                    af[i], bf_[j], acc[i][j], 0, 0, 0);
        __builtin_amdgcn_s_setprio(0);
        // counted wait: STAGE(t+1) landed; STAGE(t+2) (4 newest) may fly
        asm volatile("s_waitcnt vmcnt(4)" ::: "memory");
        __builtin_amdgcn_s_barrier();
        const int tmp = b0; b0 = b1; b1 = b2; b2 = tmp;
    }

    // drain straggler stages before reusing LDS
    asm volatile("s_waitcnt vmcnt(0)" ::: "memory");
    __syncthreads();

    // ---- epilogue: LDS-transposed, fully-coalesced C write ----
    float bias_r[4];
#pragma unroll
    for (int j = 0; j < 4; ++j) bias_r[j] = bias[n0 + wn * 64 + j * 16 + r];

    float* eb = (float*)smem;   // double-buffered [2][32][260] f32 (67 KB < 96 KB)
#pragma unroll
    for (int i = 0; i < 8; ++i) {
        float* dst = eb + (i & 1) * (32 * 260) + (wm * 16 + g * 4) * 260 + wn * 64 + r;
#pragma unroll
        for (int j = 0; j < 4; ++j)
#pragma unroll
            for (int q = 0; q < 4; ++q)
                dst[q * 260 + j * 16] = acc[i][j][q] + bias_r[j];
        __syncthreads();
        const float* srcb = eb + (i & 1) * (32 * 260);
#pragma unroll
        for (int k2 = 0; k2 < 4; ++k2) {
            const int flat = k2 * 2048 + tid * 4;
            const int rr = flat >> 8, cc = flat & 255;
            const float4 v = *(const float4*)(srcb + rr * 260 + cc);
            const long grow = m0 + (rr < 16 ? i * 16 + rr : 112 + i * 16 + rr);
            const long gcol = n0 + cc;
            if (EPI == 0) {
                ushort4 o;
                o.x = f2bf(gelu_exact(v.x));
                o.y = f2bf(gelu_exact(v.y));
                o.z = f2bf(gelu_exact(v.z));
                o.w = f2bf(gelu_exact(v.w));
                *(ushort4*)((u16*)outp + grow * N + gcol) = o;
            } else {
                const float4 rv = *(const float4*)(resid + grow * N + gcol);
                float4 o;
                o.x = v.x + rv.x; o.y = v.y + rv.y;
                o.z = v.z + rv.z; o.w = v.w + rv.w;
                *(float4*)((float*)outp + grow * N + gcol) = o;
            }
        }
    }
#undef STAGE
}

extern "C" void kernel_launch(void* const* d_in, const int* in_sizes, int n_in,
                              void* d_out, int out_size, void* d_ws, size_t ws_size,
                              hipStream_t stream) {
    const float* x      = (const float*)d_in[0];
    const float* gamma1 = (const float*)d_in[1];
    const float* beta1  = (const float*)d_in[2];
    const float* W1     = (const float*)d_in[3];
    const float* b1     = (const float*)d_in[4];
    const float* g1     = (const float*)d_in[5];
    const float* g2     = (const float*)d_in[6];
    const float* g3     = (const float*)d_in[7];
    const float* ttb    = (const float*)d_in[8];
    const float* gamma2 = (const float*)d_in[9];
    const float* beta2  = (const float*)d_in[10];

    const int ROWS = 16384, D = 1024, F = 2048;

    char* ws = (char*)d_ws;
    u16* W1T = (u16*)ws;                                  // F*D bf16 = 4 MiB
    u16* W2T = (u16*)(ws + (size_t)F * D * 2);            // D*F bf16 = 4 MiB
    float* M1 = (float*)(ws + (size_t)F * D * 4);         // 262144 f32 = 1 MiB
    char* dyn = ws + (size_t)F * D * 4 + 262144 * 4;
    const size_t fixed = (size_t)(dyn - ws);

    int Rc = ROWS;  // rows per chunk; shrink if workspace is small
    while (Rc > 256 && fixed + (size_t)Rc * 6144 > ws_size) Rc >>= 1;

    u16* xln = (u16*)dyn;                                 // Rc*1024 bf16
    u16* h   = (u16*)(dyn + (size_t)Rc * D * 2);          // Rc*2048 bf16

    transpose_cast<<<dim3(F / 32, D / 32), 256, 0, stream>>>(W1, W1T, D, F);
    tt_m1_kernel<<<262144 / 256, 256, 0, stream>>>(g1, g2, M1);
    tt_w2t_kernel<<<(D * F) / 256, 256, 0, stream>>>(M1, g3, W2T);

    float* out = (float*)d_out;
    for (int r0 = 0; r0 < ROWS; r0 += Rc) {
        ln1_kernel<<<Rc, 256, 0, stream>>>(x + (long)r0 * D, gamma1, beta1, xln);
        gemm256<0><<<(Rc / 256) * (F / 256), 512, 0, stream>>>(
            xln, W1T, h, b1, nullptr, Rc, F, D);
        gemm256<1><<<(Rc / 256) * (D / 256), 512, 0, stream>>>(
            h, W2T, out + (long)r0 * D, ttb, x + (long)r0 * D, Rc, D, F);
    }
    ln2_kernel<<<ROWS, 256, 0, stream>>>(out, gamma2, beta2);
}

// Round 5
// 291.719 us; speedup vs baseline: 1.0071x; 1.0071x over previous
//
#include <hip/hip_runtime.h>

typedef unsigned short u16;
typedef __attribute__((ext_vector_type(8))) short bf16x8;
typedef __attribute__((ext_vector_type(4))) float f32x4;

#define AS1 __attribute__((address_space(1)))
#define AS3 __attribute__((address_space(3)))

__device__ __forceinline__ void gld16(const void* g, void* l) {
    __builtin_amdgcn_global_load_lds((const AS1 void*)g, (AS3 void*)l, 16, 0, 0);
}

__device__ __forceinline__ u16 f2bf(float f) {
    unsigned int u = __float_as_uint(f);
    unsigned int r = (u >> 16) & 1u;
    u += 0x7fffu + r;
    return (u16)(u >> 16);
}

__device__ __forceinline__ float gelu_exact(float v) {
    return 0.5f * v * (1.0f + erff(v * 0.70710678118654752f));
}

// ---------------- W1 transpose + cast: W[R][C] f32 -> Wt[C][R] bf16 ----------
__global__ __launch_bounds__(256) void transpose_cast(
    const float* __restrict__ W, u16* __restrict__ Wt, int R, int C) {
    __shared__ float t[32][33];
    const int tx = threadIdx.x & 31, tg = threadIdx.x >> 5;
    const int c0 = blockIdx.x * 32, r0 = blockIdx.y * 32;
#pragma unroll
    for (int i = 0; i < 4; ++i) {
        int rr = tg + i * 8;
        t[rr][tx] = W[(long)(r0 + rr) * C + c0 + tx];
    }
    __syncthreads();
#pragma unroll
    for (int i = 0; i < 4; ++i) {
        int rr = tg + i * 8;
        Wt[(long)(c0 + rr) * R + r0 + tx] = f2bf(t[tx][rr]);
    }
}

// ---------------- TT core contraction ----------------------------------------
__global__ __launch_bounds__(256) void tt_m1_kernel(
    const float* __restrict__ g1, const float* __restrict__ g2,
    float* __restrict__ M1) {
    const int id = blockIdx.x * 256 + threadIdx.x;       // 262144
    const int t = id & 15, q = (id >> 4) & 15, p = (id >> 8) & 7;
    const int j = (id >> 11) & 15, i = id >> 15;
    float acc = 0.f;
#pragma unroll
    for (int s = 0; s < 16; ++s)
        acc += g1[(i * 8 + p) * 16 + s] * g2[((s * 16 + j) * 16 + q) * 16 + t];
    M1[id] = acc;
}

__global__ __launch_bounds__(256) void tt_w2t_kernel(
    const float* __restrict__ M1, const float* __restrict__ g3,
    u16* __restrict__ W2T) {
    const int id = blockIdx.x * 256 + threadIdx.x;       // 2097152
    const int fi = id & 2047, fo = id >> 11;
    const int i = fi >> 8, j = (fi >> 4) & 15, k = fi & 15;
    const int p = fo >> 7, q = (fo >> 3) & 15, u = fo & 7;
    const float* m = &M1[(((i * 16 + j) * 8 + p) * 16 + q) * 16];
    float acc = 0.f;
#pragma unroll
    for (int t = 0; t < 16; ++t)
        acc += m[t] * g3[(t * 16 + k) * 8 + u];
    W2T[id] = f2bf(acc);
}

// ---------------- LayerNorm 1: x f32 -> xln bf16 -----------------------------
__global__ __launch_bounds__(256) void ln1_kernel(
    const float* __restrict__ x, const float* __restrict__ gamma,
    const float* __restrict__ beta, u16* __restrict__ out) {
    const long row = blockIdx.x;
    const int tid = threadIdx.x;
    const float4 v = ((const float4*)(x + row * 1024))[tid];
    float s = v.x + v.y + v.z + v.w;
    float ss = v.x * v.x + v.y * v.y + v.z * v.z + v.w * v.w;
#pragma unroll
    for (int off = 32; off; off >>= 1) {
        s += __shfl_down(s, off, 64);
        ss += __shfl_down(ss, off, 64);
    }
    __shared__ float rs[4], rss[4];
    const int w = tid >> 6, lane = tid & 63;
    if (lane == 0) { rs[w] = s; rss[w] = ss; }
    __syncthreads();
    s = rs[0] + rs[1] + rs[2] + rs[3];
    ss = rss[0] + rss[1] + rss[2] + rss[3];
    const float mu = s * (1.0f / 1024.0f);
    const float var = ss * (1.0f / 1024.0f) - mu * mu;
    const float rstd = rsqrtf(var + 1e-5f);
    const float4 gm = ((const float4*)gamma)[tid];
    const float4 bt = ((const float4*)beta)[tid];
    ushort4 o;
    o.x = f2bf((v.x - mu) * rstd * gm.x + bt.x);
    o.y = f2bf((v.y - mu) * rstd * gm.y + bt.y);
    o.z = f2bf((v.z - mu) * rstd * gm.z + bt.z);
    o.w = f2bf((v.w - mu) * rstd * gm.w + bt.w);
    ((ushort4*)(out + row * 1024))[tid] = o;
}

// ---------------- LayerNorm 2 (in-place): z -> z + LN(z) ---------------------
__global__ __launch_bounds__(256) void ln2_kernel(
    float* __restrict__ z, const float* __restrict__ gamma,
    const float* __restrict__ beta) {
    const long row = blockIdx.x;
    const int tid = threadIdx.x;
    const float4 v = ((const float4*)(z + row * 1024))[tid];
    float s = v.x + v.y + v.z + v.w;
    float ss = v.x * v.x + v.y * v.y + v.z * v.z + v.w * v.w;
#pragma unroll
    for (int off = 32; off; off >>= 1) {
        s += __shfl_down(s, off, 64);
        ss += __shfl_down(ss, off, 64);
    }
    __shared__ float rs[4], rss[4];
    const int w = tid >> 6, lane = tid & 63;
    if (lane == 0) { rs[w] = s; rss[w] = ss; }
    __syncthreads();
    s = rs[0] + rs[1] + rs[2] + rs[3];
    ss = rss[0] + rss[1] + rss[2] + rss[3];
    const float mu = s * (1.0f / 1024.0f);
    const float var = ss * (1.0f / 1024.0f) - mu * mu;
    const float rstd = rsqrtf(var + 1e-5f);
    const float4 gm = ((const float4*)gamma)[tid];
    const float4 bt = ((const float4*)beta)[tid];
    float4 o;
    o.x = v.x + ((v.x - mu) * rstd * gm.x + bt.x);
    o.y = v.y + ((v.y - mu) * rstd * gm.y + bt.y);
    o.z = v.z + ((v.z - mu) * rstd * gm.z + bt.z);
    o.w = v.w + ((v.w - mu) * rstd * gm.w + bt.w);
    ((float4*)(z + row * 1024))[tid] = o;
}

// ---------------- 256x256 GEMM: C = A[M][K] @ Bt[N][K]^T ---------------------
// 512 threads (8 waves: 2M x 4N), BK=32, TRIPLE-buffered LDS (3 x 32 KB),
// fine-interleaved 2-phase-per-tile schedule: each phase
//   { 8-or-4 ds_read_b128 | stage one 8KB half of tile t+2 (2 gld16)
//     | barrier | lgkmcnt(0) | setprio(1) 16 MFMA setprio(0)
//     | [P2: vmcnt(4)] | barrier }
// Swizzle (corrected bank model; 8-lane groups must hit 8 distinct 16B slots
// per 128B line): element(row, c) stored at row*64 + (c ^ ((row>>1 & 3)<<4)),
// applied to staging SOURCE and frag reads.
// EPI=0: out = bf16(gelu(acc + bias[col]))
// EPI=1: out = f32(acc + bias[col] + resid[row][col])
template <int EPI>
__global__ __launch_bounds__(512, 2) void gemm256(
    const u16* __restrict__ A, const u16* __restrict__ Bt,
    void* __restrict__ outp, const float* __restrict__ bias,
    const float* __restrict__ resid, int M, int N, int K) {
    __shared__ char smem[98304];
    const int tid = threadIdx.x;
    int b = blockIdx.x;
    const int nwg = gridDim.x;
    if ((nwg & 7) == 0 && nwg >= 8) {   // XCD-aware swizzle (bijective)
        const int per = nwg >> 3;
        b = (b & 7) * per + (b >> 3);
    }
    const int NT = N >> 8;
    const int mt = b / NT, nt = b - mt * NT;
    const long m0 = (long)mt << 8, n0 = (long)nt << 8;
    const int NTK = K >> 5;

    const int lane = tid & 63, wid = tid >> 6;
    const int wm = wid >> 2, wn = wid & 3;
    const int r = lane & 15, g = lane >> 4;

    // staging: one gld16 covers one 8 KB half (512 thr x 16 B), rows lin>>6
    const int lin = tid * 16;
    const int srow = lin >> 6;                                   // 0..127
    const int scol = ((lin & 63) ^ (((lin >> 7) & 3) << 4)) >> 1;  // elements

    const u16* pA0 = A + (m0 + srow) * (long)K + scol;        // rows 0..127
    const u16* pA1 = A + (m0 + 128 + srow) * (long)K + scol;  // rows 128..255
    const u16* pB0 = Bt + (n0 + srow) * (long)K + scol;
    const u16* pB1 = Bt + (n0 + 128 + srow) * (long)K + scol;

    // frag-read swizzle: per-thread constant
    const int sx = ((r >> 1) & 3) << 4;
    const int ac = (g * 16) ^ sx;
    const int arow = wm * 128;   // wave's A row base within 256-row tile
    const int brow = wn * 64;    // wave's B row base within 256-row tile

    f32x4 acc[8][4] = {};

    // ---- prologue: stage tiles 0 (buf0) and 1 (buf1); wait tile0 landed ----
    gld16(pA0, smem + lin);            gld16(pA1, smem + 8192 + lin);
    gld16(pB0, smem + 16384 + lin);    gld16(pB1, smem + 24576 + lin);
    if (NTK > 1) { pA0 += 32; pA1 += 32; pB0 += 32; pB1 += 32; }
    gld16(pA0, smem + 32768 + lin);          gld16(pA1, smem + 32768 + 8192 + lin);
    gld16(pB0, smem + 32768 + 16384 + lin);  gld16(pB1, smem + 32768 + 24576 + lin);
    if (NTK > 2) { pA0 += 32; pA1 += 32; pB0 += 32; pB1 += 32; }
    asm volatile("s_waitcnt vmcnt(4)" ::: "memory");
    __builtin_amdgcn_s_barrier();
    __builtin_amdgcn_sched_barrier(0);

    int cb = 0, sb = 2;   // compute buf = t%3, stage buf = (t+2)%3
    for (int t = 0; t < NTK; ++t) {
        const char* Ab = smem + cb * 32768;
        const char* Bb = smem + cb * 32768 + 16384;
        char* Sb = smem + sb * 32768;
        bf16x8 af[4], bf_[4];

        // ---- P1: M-low quadrant; stage A halves of tile t+2 ----
#pragma unroll
        for (int i = 0; i < 4; ++i)
            af[i] = *(const bf16x8*)(Ab + ((arow + i * 16 + r) * 64 + ac));
#pragma unroll
        for (int j = 0; j < 4; ++j)
            bf_[j] = *(const bf16x8*)(Bb + ((brow + j * 16 + r) * 64 + ac));
        gld16(pA0, Sb + lin);
        gld16(pA1, Sb + 8192 + lin);
        __builtin_amdgcn_s_barrier();
        asm volatile("s_waitcnt lgkmcnt(0)" ::: "memory");
        __builtin_amdgcn_sched_barrier(0);
        __builtin_amdgcn_s_setprio(1);
#pragma unroll
        for (int i = 0; i < 4; ++i)
#pragma unroll
            for (int j = 0; j < 4; ++j)
                acc[i][j] = __builtin_amdgcn_mfma_f32_16x16x32_bf16(
                    af[i], bf_[j], acc[i][j], 0, 0, 0);
        __builtin_amdgcn_s_setprio(0);
        __builtin_amdgcn_s_barrier();
        __builtin_amdgcn_sched_barrier(0);

        // ---- P2: M-high quadrant (B reused in regs); stage B halves ----
#pragma unroll
        for (int i = 0; i < 4; ++i)
            af[i] = *(const bf16x8*)(Ab + ((arow + (i + 4) * 16 + r) * 64 + ac));
        gld16(pB0, Sb + 16384 + lin);
        gld16(pB1, Sb + 24576 + lin);
        __builtin_amdgcn_s_barrier();
        asm volatile("s_waitcnt lgkmcnt(0)" ::: "memory");
        __builtin_amdgcn_sched_barrier(0);
        __builtin_amdgcn_s_setprio(1);
#pragma unroll
        for (int i = 0; i < 4; ++i)
#pragma unroll
            for (int j = 0; j < 4; ++j)
                acc[i + 4][j] = __builtin_amdgcn_mfma_f32_16x16x32_bf16(
                    af[i], bf_[j], acc[i + 4][j], 0, 0, 0);
        __builtin_amdgcn_s_setprio(0);
        // counted wait: only tile t+2's 4 stages may remain in flight
        asm volatile("s_waitcnt vmcnt(4)" ::: "memory");
        __builtin_amdgcn_s_barrier();
        __builtin_amdgcn_sched_barrier(0);

        if (t + 3 < NTK) { pA0 += 32; pA1 += 32; pB0 += 32; pB1 += 32; }
        cb = cb == 2 ? 0 : cb + 1;
        sb = sb == 2 ? 0 : sb + 1;
    }

    // drain straggler stages before reusing LDS
    asm volatile("s_waitcnt vmcnt(0)" ::: "memory");
    __syncthreads();

    // ---- epilogue: LDS-transposed, fully-coalesced C write ----
    float bias_r[4];
#pragma unroll
    for (int j = 0; j < 4; ++j) bias_r[j] = bias[n0 + wn * 64 + j * 16 + r];

    float* eb = (float*)smem;   // double-buffered [2][32][260] f32 (67 KB < 96 KB)
#pragma unroll
    for (int i = 0; i < 8; ++i) {
        float* dst = eb + (i & 1) * (32 * 260) + (wm * 16 + g * 4) * 260 + wn * 64 + r;
#pragma unroll
        for (int j = 0; j < 4; ++j)
#pragma unroll
            for (int q = 0; q < 4; ++q)
                dst[q * 260 + j * 16] = acc[i][j][q] + bias_r[j];
        __syncthreads();
        const float* srcb = eb + (i & 1) * (32 * 260);
#pragma unroll
        for (int k2 = 0; k2 < 4; ++k2) {
            const int flat = k2 * 2048 + tid * 4;
            const int rr = flat >> 8, cc = flat & 255;
            const float4 v = *(const float4*)(srcb + rr * 260 + cc);
            const long grow = m0 + (rr < 16 ? i * 16 + rr : 112 + i * 16 + rr);
            const long gcol = n0 + cc;
            if (EPI == 0) {
                ushort4 o;
                o.x = f2bf(gelu_exact(v.x));
                o.y = f2bf(gelu_exact(v.y));
                o.z = f2bf(gelu_exact(v.z));
                o.w = f2bf(gelu_exact(v.w));
                *(ushort4*)((u16*)outp + grow * N + gcol) = o;
            } else {
                const float4 rv = *(const float4*)(resid + grow * N + gcol);
                float4 o;
                o.x = v.x + rv.x; o.y = v.y + rv.y;
                o.z = v.z + rv.z; o.w = v.w + rv.w;
                *(float4*)((float*)outp + grow * N + gcol) = o;
            }
        }
    }
}

extern "C" void kernel_launch(void* const* d_in, const int* in_sizes, int n_in,
                              void* d_out, int out_size, void* d_ws, size_t ws_size,
                              hipStream_t stream) {
    const float* x      = (const float*)d_in[0];
    const float* gamma1 = (const float*)d_in[1];
    const float* beta1  = (const float*)d_in[2];
    const float* W1     = (const float*)d_in[3];
    const float* b1     = (const float*)d_in[4];
    const float* g1     = (const float*)d_in[5];
    const float* g2     = (const float*)d_in[6];
    const float* g3     = (const float*)d_in[7];
    const float* ttb    = (const float*)d_in[8];
    const float* gamma2 = (const float*)d_in[9];
    const float* beta2  = (const float*)d_in[10];

    const int ROWS = 16384, D = 1024, F = 2048;

    char* ws = (char*)d_ws;
    u16* W1T = (u16*)ws;                                  // F*D bf16 = 4 MiB
    u16* W2T = (u16*)(ws + (size_t)F * D * 2);            // D*F bf16 = 4 MiB
    float* M1 = (float*)(ws + (size_t)F * D * 4);         // 262144 f32 = 1 MiB
    char* dyn = ws + (size_t)F * D * 4 + 262144 * 4;
    const size_t fixed = (size_t)(dyn - ws);

    int Rc = ROWS;  // rows per chunk; shrink if workspace is small
    while (Rc > 256 && fixed + (size_t)Rc * 6144 > ws_size) Rc >>= 1;

    u16* xln = (u16*)dyn;                                 // Rc*1024 bf16
    u16* h   = (u16*)(dyn + (size_t)Rc * D * 2);          // Rc*2048 bf16

    transpose_cast<<<dim3(F / 32, D / 32), 256, 0, stream>>>(W1, W1T, D, F);
    tt_m1_kernel<<<262144 / 256, 256, 0, stream>>>(g1, g2, M1);
    tt_w2t_kernel<<<(D * F) / 256, 256, 0, stream>>>(M1, g3, W2T);

    float* out = (float*)d_out;
    for (int r0 = 0; r0 < ROWS; r0 += Rc) {
        ln1_kernel<<<Rc, 256, 0, stream>>>(x + (long)r0 * D, gamma1, beta1, xln);
        gemm256<0><<<(Rc / 256) * (F / 256), 512, 0, stream>>>(
            xln, W1T, h, b1, nullptr, Rc, F, D);
        gemm256<1><<<(Rc / 256) * (D / 256), 512, 0, stream>>>(
            h, W2T, out + (long)r0 * D, ttb, x + (long)r0 * D, Rc, D, F);
    }
    ln2_kernel<<<ROWS, 256, 0, stream>>>(out, gamma2, beta2);
}

// Round 6
// 288.252 us; speedup vs baseline: 1.0192x; 1.0120x over previous
//
#include <hip/hip_runtime.h>

typedef unsigned short u16;
typedef __attribute__((ext_vector_type(8))) short bf16x8;
typedef __attribute__((ext_vector_type(4))) float f32x4;

#define AS1 __attribute__((address_space(1)))
#define AS3 __attribute__((address_space(3)))

__device__ __forceinline__ void gld16(const void* g, void* l) {
    __builtin_amdgcn_global_load_lds((const AS1 void*)g, (AS3 void*)l, 16, 0, 0);
}

__device__ __forceinline__ u16 f2bf(float f) {
    unsigned int u = __float_as_uint(f);
    unsigned int r = (u >> 16) & 1u;
    u += 0x7fffu + r;
    return (u16)(u >> 16);
}

__device__ __forceinline__ float gelu_exact(float v) {
    return 0.5f * v * (1.0f + erff(v * 0.70710678118654752f));
}

// ---------------- W1 transpose + cast: W[R][C] f32 -> Wt[C][R] bf16 ----------
__global__ __launch_bounds__(256) void transpose_cast(
    const float* __restrict__ W, u16* __restrict__ Wt, int R, int C) {
    __shared__ float t[32][33];
    const int tx = threadIdx.x & 31, tg = threadIdx.x >> 5;
    const int c0 = blockIdx.x * 32, r0 = blockIdx.y * 32;
#pragma unroll
    for (int i = 0; i < 4; ++i) {
        int rr = tg + i * 8;
        t[rr][tx] = W[(long)(r0 + rr) * C + c0 + tx];
    }
    __syncthreads();
#pragma unroll
    for (int i = 0; i < 4; ++i) {
        int rr = tg + i * 8;
        Wt[(long)(c0 + rr) * R + r0 + tx] = f2bf(t[tx][rr]);
    }
}

// ---------------- TT core contraction ----------------------------------------
__global__ __launch_bounds__(256) void tt_m1_kernel(
    const float* __restrict__ g1, const float* __restrict__ g2,
    float* __restrict__ M1) {
    const int id = blockIdx.x * 256 + threadIdx.x;       // 262144
    const int t = id & 15, q = (id >> 4) & 15, p = (id >> 8) & 7;
    const int j = (id >> 11) & 15, i = id >> 15;
    float acc = 0.f;
#pragma unroll
    for (int s = 0; s < 16; ++s)
        acc += g1[(i * 8 + p) * 16 + s] * g2[((s * 16 + j) * 16 + q) * 16 + t];
    M1[id] = acc;
}

__global__ __launch_bounds__(256) void tt_w2t_kernel(
    const float* __restrict__ M1, const float* __restrict__ g3,
    u16* __restrict__ W2T) {
    const int id = blockIdx.x * 256 + threadIdx.x;       // 2097152
    const int fi = id & 2047, fo = id >> 11;
    const int i = fi >> 8, j = (fi >> 4) & 15, k = fi & 15;
    const int p = fo >> 7, q = (fo >> 3) & 15, u = fo & 7;
    const float* m = &M1[(((i * 16 + j) * 8 + p) * 16 + q) * 16];
    float acc = 0.f;
#pragma unroll
    for (int t = 0; t < 16; ++t)
        acc += m[t] * g3[(t * 16 + k) * 8 + u];
    W2T[id] = f2bf(acc);
}

// ---------------- LayerNorm 1: x f32 -> xln bf16 -----------------------------
__global__ __launch_bounds__(256) void ln1_kernel(
    const float* __restrict__ x, const float* __restrict__ gamma,
    const float* __restrict__ beta, u16* __restrict__ out) {
    const long row = blockIdx.x;
    const int tid = threadIdx.x;
    const float4 v = ((const float4*)(x + row * 1024))[tid];
    float s = v.x + v.y + v.z + v.w;
    float ss = v.x * v.x + v.y * v.y + v.z * v.z + v.w * v.w;
#pragma unroll
    for (int off = 32; off; off >>= 1) {
        s += __shfl_down(s, off, 64);
        ss += __shfl_down(ss, off, 64);
    }
    __shared__ float rs[4], rss[4];
    const int w = tid >> 6, lane = tid & 63;
    if (lane == 0) { rs[w] = s; rss[w] = ss; }
    __syncthreads();
    s = rs[0] + rs[1] + rs[2] + rs[3];
    ss = rss[0] + rss[1] + rss[2] + rss[3];
    const float mu = s * (1.0f / 1024.0f);
    const float var = ss * (1.0f / 1024.0f) - mu * mu;
    const float rstd = rsqrtf(var + 1e-5f);
    const float4 gm = ((const float4*)gamma)[tid];
    const float4 bt = ((const float4*)beta)[tid];
    ushort4 o;
    o.x = f2bf((v.x - mu) * rstd * gm.x + bt.x);
    o.y = f2bf((v.y - mu) * rstd * gm.y + bt.y);
    o.z = f2bf((v.z - mu) * rstd * gm.z + bt.z);
    o.w = f2bf((v.w - mu) * rstd * gm.w + bt.w);
    ((ushort4*)(out + row * 1024))[tid] = o;
}

// ---------------- LayerNorm 2 (in-place): z -> z + LN(z) ---------------------
__global__ __launch_bounds__(256) void ln2_kernel(
    float* __restrict__ z, const float* __restrict__ gamma,
    const float* __restrict__ beta) {
    const long row = blockIdx.x;
    const int tid = threadIdx.x;
    const float4 v = ((const float4*)(z + row * 1024))[tid];
    float s = v.x + v.y + v.z + v.w;
    float ss = v.x * v.x + v.y * v.y + v.z * v.z + v.w * v.w;
#pragma unroll
    for (int off = 32; off; off >>= 1) {
        s += __shfl_down(s, off, 64);
        ss += __shfl_down(ss, off, 64);
    }
    __shared__ float rs[4], rss[4];
    const int w = tid >> 6, lane = tid & 63;
    if (lane == 0) { rs[w] = s; rss[w] = ss; }
    __syncthreads();
    s = rs[0] + rs[1] + rs[2] + rs[3];
    ss = rss[0] + rss[1] + rss[2] + rss[3];
    const float mu = s * (1.0f / 1024.0f);
    const float var = ss * (1.0f / 1024.0f) - mu * mu;
    const float rstd = rsqrtf(var + 1e-5f);
    const float4 gm = ((const float4*)gamma)[tid];
    const float4 bt = ((const float4*)beta)[tid];
    float4 o;
    o.x = v.x + ((v.x - mu) * rstd * gm.x + bt.x);
    o.y = v.y + ((v.y - mu) * rstd * gm.y + bt.y);
    o.z = v.z + ((v.z - mu) * rstd * gm.z + bt.z);
    o.w = v.w + ((v.w - mu) * rstd * gm.w + bt.w);
    ((float4*)(z + row * 1024))[tid] = o;
}

// ---------------- 256x256 4-phase GEMM: C = A[M][K] @ Bt[N][K]^T -------------
// R2 structure (m201-like: 2 barriers/phase, counted vmcnt(4), dbuf BK=64,
// A(t+1) staged at P1 into other buf, B(t+2) staged at P4 into dead slots)
// + R3-validated conflict-free swizzle: byte ^= (row&7)<<4 on BOTH sides.
// EPI=0: out = bf16(gelu(acc + bias[col]))
// EPI=1: out = f32(acc + bias[col] + resid[row][col])
template <int EPI>
__global__ __launch_bounds__(512, 2) void gemm256(
    const u16* __restrict__ A, const u16* __restrict__ Bt,
    void* __restrict__ outp, const float* __restrict__ bias,
    const float* __restrict__ resid, int M, int N, int K) {
    __shared__ char smem[131072];
    const int tid = threadIdx.x;
    int b = blockIdx.x;
    const int nwg = gridDim.x;
    if ((nwg & 7) == 0 && nwg >= 8) {   // XCD-aware swizzle (bijective)
        const int per = nwg >> 3;
        b = (b & 7) * per + (b >> 3);
    }
    const int NT = N >> 8;
    const int mt = b / NT, nt = b - mt * NT;
    const long m0 = (long)mt << 8, n0 = (long)nt << 8;
    const int NTK = K >> 6;

    const int lane = tid & 63, wid = tid >> 6;
    const int wm = wid >> 2, wn = wid & 3;
    const int r = lane & 15, g = lane >> 4;

    // staging: linear LDS dest; source column pre-swizzled with the SAME
    // involution the reads use: byte ^= ((row&7)<<4)  [R3-validated: 0 conflicts]
    const int lin0 = tid * 16, lin1 = tid * 16 + 8192;
    const int sr0 = lin0 >> 7, sc0 = ((lin0 & 127) ^ (((lin0 >> 7) & 7) << 4)) >> 1;
    const int sr1 = lin1 >> 7, sc1 = ((lin1 & 127) ^ (((lin1 >> 7) & 7) << 4)) >> 1;

#define STAGE_HALF(G, rowbase, kt, ldsoff)                                        \
    do {                                                                          \
        gld16((G) + ((rowbase) + sr0) * (long)K + (kt) * 64 + sc0,                \
              smem + (ldsoff) + lin0);                                            \
        gld16((G) + ((rowbase) + sr1) * (long)K + (kt) * 64 + sc1,                \
              smem + (ldsoff) + lin1);                                            \
    } while (0)
#define STAGE_A(kt, pb)                                                           \
    do {                                                                          \
        const int kc = (kt) < NTK ? (kt) : NTK - 1;                               \
        STAGE_HALF(A, m0, kc, (pb) * 65536);                                      \
        STAGE_HALF(A, m0 + 128, kc, (pb) * 65536 + 16384);                        \
    } while (0)
#define STAGE_B(kt, pb)                                                           \
    do {                                                                          \
        const int kc = (kt) < NTK ? (kt) : NTK - 1;                               \
        STAGE_HALF(Bt, n0, kc, (pb) * 65536 + 32768);                             \
        STAGE_HALF(Bt, n0 + 128, kc, (pb) * 65536 + 49152);                       \
    } while (0)

    // read-side swizzle: per-thread constant XOR on byte bits 4-6.
    // ks1 (+64) XORed as a whole (sx carries bit 6).
    const int sx = (r & 7) << 4;
    const int ac0 = (g * 16) ^ sx;         // ks0 col-byte
    const int ac1 = (g * 16 + 64) ^ sx;    // ks1 col-byte
    const int brow = (wn & 1) * 64;

    f32x4 acc[8][4] = {};

    // ---- prologue: tile0 A+B, tile1 B; allow tile1.B outstanding ----
    STAGE_A(0, 0);
    STAGE_B(0, 0);
    STAGE_B(1, 1);
    asm volatile("s_waitcnt vmcnt(4)" ::: "memory");
    __builtin_amdgcn_s_barrier();
    __builtin_amdgcn_sched_barrier(0);

    for (int t = 0; t < NTK; ++t) {
        const int p = t & 1;
        const char* Ab = smem + p * 65536 + wm * 16384;
        const char* Bb = smem + p * 65536 + 32768 + (wn >> 1) * 16384;
        bf16x8 af[4], bf_[4];

        // ---- P1: ks0, mi 0-3 (+ stage next tile's A into other buf) ----
#pragma unroll
        for (int i = 0; i < 4; ++i)
            af[i] = *(const bf16x8*)(Ab + ((i * 16 + r) * 128 + ac0));
#pragma unroll
        for (int i = 0; i < 4; ++i)
            bf_[i] = *(const bf16x8*)(Bb + ((brow + i * 16 + r) * 128 + ac0));
        STAGE_A(t + 1, p ^ 1);
        __builtin_amdgcn_s_barrier();
        __builtin_amdgcn_sched_barrier(0);
        __builtin_amdgcn_s_setprio(1);
#pragma unroll
        for (int i = 0; i < 4; ++i)
#pragma unroll
            for (int j = 0; j < 4; ++j)
                acc[i][j] = __builtin_amdgcn_mfma_f32_16x16x32_bf16(
                    af[i], bf_[j], acc[i][j], 0, 0, 0);
        __builtin_amdgcn_s_setprio(0);
        __builtin_amdgcn_s_barrier();
        __builtin_amdgcn_sched_barrier(0);

        // ---- P2: ks0, mi 4-7 (B frags reused from regs) ----
#pragma unroll
        for (int i = 0; i < 4; ++i)
            af[i] = *(const bf16x8*)(Ab + (((i + 4) * 16 + r) * 128 + ac0));
        __builtin_amdgcn_s_barrier();
        __builtin_amdgcn_sched_barrier(0);
        __builtin_amdgcn_s_setprio(1);
#pragma unroll
        for (int i = 0; i < 4; ++i)
#pragma unroll
            for (int j = 0; j < 4; ++j)
                acc[i + 4][j] = __builtin_amdgcn_mfma_f32_16x16x32_bf16(
                    af[i], bf_[j], acc[i + 4][j], 0, 0, 0);
        __builtin_amdgcn_s_setprio(0);
        __builtin_amdgcn_s_barrier();
        __builtin_amdgcn_sched_barrier(0);

        // ---- P3: ks1, mi 0-3 ----
#pragma unroll
        for (int i = 0; i < 4; ++i)
            af[i] = *(const bf16x8*)(Ab + ((i * 16 + r) * 128 + ac1));
#pragma unroll
        for (int i = 0; i < 4; ++i)
            bf_[i] = *(const bf16x8*)(Bb + ((brow + i * 16 + r) * 128 + ac1));
        __builtin_amdgcn_s_barrier();
        __builtin_amdgcn_sched_barrier(0);
        __builtin_amdgcn_s_setprio(1);
#pragma unroll
        for (int i = 0; i < 4; ++i)
#pragma unroll
            for (int j = 0; j < 4; ++j)
                acc[i][j] = __builtin_amdgcn_mfma_f32_16x16x32_bf16(
                    af[i], bf_[j], acc[i][j], 0, 0, 0);
        __builtin_amdgcn_s_setprio(0);
        __builtin_amdgcn_s_barrier();
        __builtin_amdgcn_sched_barrier(0);

        // ---- P4: ks1, mi 4-7 (+ stage tile t+2's B into current buf) ----
#pragma unroll
        for (int i = 0; i < 4; ++i)
            af[i] = *(const bf16x8*)(Ab + (((i + 4) * 16 + r) * 128 + ac1));
        STAGE_B(t + 2, p);
        __builtin_amdgcn_s_barrier();
        __builtin_amdgcn_sched_barrier(0);
        __builtin_amdgcn_s_setprio(1);
#pragma unroll
        for (int i = 0; i < 4; ++i)
#pragma unroll
            for (int j = 0; j < 4; ++j)
                acc[i + 4][j] = __builtin_amdgcn_mfma_f32_16x16x32_bf16(
                    af[i], bf_[j], acc[i + 4][j], 0, 0, 0);
        __builtin_amdgcn_s_setprio(0);
        // ---- tile boundary: counted wait, never drain to 0 ----
        asm volatile("s_waitcnt vmcnt(4)" ::: "memory");
        __builtin_amdgcn_s_barrier();
        __builtin_amdgcn_sched_barrier(0);
    }

    // drain straggler (clamped) stages before reusing LDS
    asm volatile("s_waitcnt vmcnt(0)" ::: "memory");
    __syncthreads();

    // ---- epilogue: LDS-transposed, fully-coalesced C write ----
    float bias_r[4];
#pragma unroll
    for (int j = 0; j < 4; ++j) bias_r[j] = bias[n0 + wn * 64 + j * 16 + r];

    float* eb = (float*)smem;   // double-buffered [2][32][260] f32
#pragma unroll
    for (int i = 0; i < 8; ++i) {
        float* dst = eb + (i & 1) * (32 * 260) + (wm * 16 + g * 4) * 260 + wn * 64 + r;
#pragma unroll
        for (int j = 0; j < 4; ++j)
#pragma unroll
            for (int q = 0; q < 4; ++q)
                dst[q * 260 + j * 16] = acc[i][j][q] + bias_r[j];
        __syncthreads();
        const float* srcb = eb + (i & 1) * (32 * 260);
#pragma unroll
        for (int k2 = 0; k2 < 4; ++k2) {
            const int flat = k2 * 2048 + tid * 4;
            const int rr = flat >> 8, cc = flat & 255;
            const float4 v = *(const float4*)(srcb + rr * 260 + cc);
            const long grow = m0 + (rr < 16 ? i * 16 + rr : 112 + i * 16 + rr);
            const long gcol = n0 + cc;
            if (EPI == 0) {
                ushort4 o;
                o.x = f2bf(gelu_exact(v.x));
                o.y = f2bf(gelu_exact(v.y));
                o.z = f2bf(gelu_exact(v.z));
                o.w = f2bf(gelu_exact(v.w));
                *(ushort4*)((u16*)outp + grow * N + gcol) = o;
            } else {
                const float4 rv = *(const float4*)(resid + grow * N + gcol);
                float4 o;
                o.x = v.x + rv.x; o.y = v.y + rv.y;
                o.z = v.z + rv.z; o.w = v.w + rv.w;
                *(float4*)((float*)outp + grow * N + gcol) = o;
            }
        }
    }
#undef STAGE_HALF
#undef STAGE_A
#undef STAGE_B
}

extern "C" void kernel_launch(void* const* d_in, const int* in_sizes, int n_in,
                              void* d_out, int out_size, void* d_ws, size_t ws_size,
                              hipStream_t stream) {
    const float* x      = (const float*)d_in[0];
    const float* gamma1 = (const float*)d_in[1];
    const float* beta1  = (const float*)d_in[2];
    const float* W1     = (const float*)d_in[3];
    const float* b1     = (const float*)d_in[4];
    const float* g1     = (const float*)d_in[5];
    const float* g2     = (const float*)d_in[6];
    const float* g3     = (const float*)d_in[7];
    const float* ttb    = (const float*)d_in[8];
    const float* gamma2 = (const float*)d_in[9];
    const float* beta2  = (const float*)d_in[10];

    const int ROWS = 16384, D = 1024, F = 2048;

    char* ws = (char*)d_ws;
    u16* W1T = (u16*)ws;                                  // F*D bf16 = 4 MiB
    u16* W2T = (u16*)(ws + (size_t)F * D * 2);            // D*F bf16 = 4 MiB
    float* M1 = (float*)(ws + (size_t)F * D * 4);         // 262144 f32 = 1 MiB
    char* dyn = ws + (size_t)F * D * 4 + 262144 * 4;
    const size_t fixed = (size_t)(dyn - ws);

    int Rc = ROWS;  // rows per chunk; shrink if workspace is small
    while (Rc > 256 && fixed + (size_t)Rc * 6144 > ws_size) Rc >>= 1;

    u16* xln = (u16*)dyn;                                 // Rc*1024 bf16
    u16* h   = (u16*)(dyn + (size_t)Rc * D * 2);          // Rc*2048 bf16

    transpose_cast<<<dim3(F / 32, D / 32), 256, 0, stream>>>(W1, W1T, D, F);
    tt_m1_kernel<<<262144 / 256, 256, 0, stream>>>(g1, g2, M1);
    tt_w2t_kernel<<<(D * F) / 256, 256, 0, stream>>>(M1, g3, W2T);

    float* out = (float*)d_out;
    for (int r0 = 0; r0 < ROWS; r0 += Rc) {
        ln1_kernel<<<Rc, 256, 0, stream>>>(x + (long)r0 * D, gamma1, beta1, xln);
        gemm256<0><<<(Rc / 256) * (F / 256), 512, 0, stream>>>(
            xln, W1T, h, b1, nullptr, Rc, F, D);
        gemm256<1><<<(Rc / 256) * (D / 256), 512, 0, stream>>>(
            h, W2T, out + (long)r0 * D, ttb, x + (long)r0 * D, Rc, D, F);
    }
    ln2_kernel<<<ROWS, 256, 0, stream>>>(out, gamma2, beta2);
}